// Round 20
// baseline (116.277 us; speedup 1.0000x reference)
//
#include <hip/hip_runtime.h>
#include <hip/hip_bf16.h>
#include <stdint.h>

#define FEAT 1024
#define NALL 1000
#define NCLS 100

typedef __attribute__((ext_vector_type(8))) short short8;
typedef __attribute__((ext_vector_type(4))) float f32x4;
typedef __attribute__((ext_vector_type(4))) unsigned short us4;

__device__ __forceinline__ unsigned short f2bf(float f) {
    union { float f; uint32_t u; } v; v.f = f;
    uint32_t u = v.u;
    return (unsigned short)((u + 0x7FFFu + ((u >> 16) & 1u)) >> 16);
}

__device__ __forceinline__ void gload16(const void* g, void* l) {
    __builtin_amdgcn_global_load_lds((__attribute__((address_space(1))) void*)g,
                                     (__attribute__((address_space(3))) void*)l,
                                     16, 0, 0);
}

// K1 (merged prep): blocks [0,4096): x -> bf16 + row sum-sq
//                   blocks [4096,5120): protos -> bf16 (pad rows 1000.. = 0)
//                   blocks [5120,6144): enc_w transpose -> bf16 wt[n][k]=w[k][n]
//                   block 6144: zero psq
__global__ __launch_bounds__(256) void k_prep_all(const float* __restrict__ x,
                                                  unsigned short* __restrict__ xb,
                                                  float* __restrict__ xsq,
                                                  const float* __restrict__ p,
                                                  unsigned short* __restrict__ pb,
                                                  const float* __restrict__ w,
                                                  unsigned short* __restrict__ wt,
                                                  float* __restrict__ psq) {
    __shared__ float tile[32][33];
    int b = blockIdx.x;
    if (b < 4096) {
        int row = b * 4 + (threadIdx.x >> 6);
        int lane = threadIdx.x & 63;
        const float4* xr = (const float4*)(x + (size_t)row * FEAT);
        float s = 0.f;
#pragma unroll
        for (int i = 0; i < 4; ++i) {
            float4 v = xr[lane + i * 64];
            s += v.x * v.x + v.y * v.y + v.z * v.z + v.w * v.w;
            us4 o;
            o[0] = f2bf(v.x); o[1] = f2bf(v.y); o[2] = f2bf(v.z); o[3] = f2bf(v.w);
            *(us4*)(xb + (size_t)row * FEAT + (size_t)(lane + i * 64) * 4) = o;
        }
#pragma unroll
        for (int off = 32; off; off >>= 1) s += __shfl_xor(s, off);
        if (lane == 0) xsq[row] = s;
    } else if (b < 5120) {
        int row = b - 4096, t = threadIdx.x;
        us4 o;
        if (row < NALL) {
            float4 v = ((const float4*)(p + (size_t)row * FEAT))[t];
            o[0] = f2bf(v.x); o[1] = f2bf(v.y); o[2] = f2bf(v.z); o[3] = f2bf(v.w);
        } else {
            o[0] = 0; o[1] = 0; o[2] = 0; o[3] = 0;
        }
        *(us4*)(pb + (size_t)row * FEAT + (size_t)t * 4) = o;
    } else if (b < 6144) {
        int bb = b - 5120;
        int bx = bb & 31, by = bb >> 5;
        int tx = threadIdx.x & 31, ty = threadIdx.x >> 5;
#pragma unroll
        for (int i = 0; i < 4; ++i) {
            int r = by * 32 + ty + i * 8;
            tile[ty + i * 8][tx] = w[(size_t)r * FEAT + bx * 32 + tx];
        }
        __syncthreads();
#pragma unroll
        for (int i = 0; i < 4; ++i) {
            int r = bx * 32 + ty + i * 8;
            wt[(size_t)r * FEAT + by * 32 + tx] = f2bf(tile[tx][ty + i * 8]);
        }
    } else {
#pragma unroll
        for (int i = 0; i < 4; ++i) {
            int idx = threadIdx.x + i * 256;
            if (idx < NALL) psq[idx] = 0.f;
        }
    }
}

// K2: encoder GEMM ep = protos @ enc_w + b — 64x64 tiles, 256 blocks, with
// FUSED psq (bf16-rounded squares, shfl-reduced, one atomicAdd/row/wave).
// epb rows class-major permuted: n' = (n%100)*10 + n/100.
__global__ __launch_bounds__(256) void k_enc_gemm(const unsigned short* __restrict__ A,
                                                  const unsigned short* __restrict__ B,
                                                  const float* __restrict__ bias,
                                                  unsigned short* __restrict__ epb,
                                                  float* __restrict__ psq) {
    __shared__ __align__(16) char smem[16384];   // A [64][64] @0, B [64][64] @8192
    int bm0 = (blockIdx.x >> 4) * 64;
    int bn0 = (blockIdx.x & 15) * 64;
    int tid = threadIdx.x, lane = tid & 63, wid = tid >> 6;
    int wm = wid >> 1, wn = wid & 1;
    int ls = lane >> 4, lf = lane & 15;
    f32x4 acc[2][2] = {};
    for (int k0 = 0; k0 < FEAT; k0 += 64) {
        __syncthreads();
#pragma unroll
        for (int i = 0; i < 2; ++i) {
            int ci = wid + i * 4;
            int r = ci * 8 + (lane >> 3), c = (lane & 7) * 8;
            gload16(A + (size_t)(bm0 + r) * FEAT + k0 + c, smem + ci * 1024);
            gload16(B + (size_t)(bn0 + r) * FEAT + k0 + c, smem + 8192 + ci * 1024);
        }
        __syncthreads();
#pragma unroll
        for (int kk = 0; kk < 64; kk += 32) {
            short8 a[2], b[2];
#pragma unroll
            for (int f = 0; f < 2; ++f) {
                a[f] = *(const short8*)(smem + (wm * 32 + f * 16 + lf) * 128 + (kk + ls * 8) * 2);
                b[f] = *(const short8*)(smem + 8192 + (wn * 32 + f * 16 + lf) * 128 + (kk + ls * 8) * 2);
            }
#pragma unroll
            for (int fm = 0; fm < 2; ++fm)
#pragma unroll
                for (int fn = 0; fn < 2; ++fn)
                    acc[fm][fn] = __builtin_amdgcn_mfma_f32_16x16x32_bf16(a[fm], b[fn], acc[fm][fn], 0, 0, 0);
        }
    }
    int tr = ls * 4, tc = lf;
    float sq[2][4] = {};
#pragma unroll
    for (int fn = 0; fn < 2; ++fn) {
        int col = bn0 + wn * 32 + fn * 16 + tc;
        float bb = bias[col];
#pragma unroll
        for (int fm = 0; fm < 2; ++fm) {
#pragma unroll
            for (int r = 0; r < 4; ++r) {
                int row = bm0 + wm * 32 + fm * 16 + tr + r;
                if (row < NALL) {
                    unsigned short us = f2bf(acc[fm][fn][r] + bb);
                    union { uint32_t u; float f; } c; c.u = ((uint32_t)us) << 16;
                    sq[fm][r] += c.f * c.f;
                    int pr = (row % 100) * 10 + row / 100;
                    epb[(size_t)pr * FEAT + col] = us;
                }
            }
        }
    }
#pragma unroll
    for (int fm = 0; fm < 2; ++fm)
#pragma unroll
        for (int r = 0; r < 4; ++r) {
            float s = sq[fm][r];
            s += __shfl_xor(s, 1); s += __shfl_xor(s, 2);
            s += __shfl_xor(s, 4); s += __shfl_xor(s, 8);
            int row = bm0 + wm * 32 + fm * 16 + tr + r;
            if (lf == 0 && row < NALL) {
                int pr = (row % 100) * 10 + row / 100;
                atomicAdd(psq + pr, s);
            }
        }
}

// K3: main GEMM + fused sqrt + min-over-10 — r12 schedule, BN 80->160.
// BM=128, BN=160 (16 classes x 10 protos, class-aligned), BK=64, 4 waves 4Mx1N,
// wave-tile 32x160, acc[2][10] (~80 VGPR; bare launch_bounds, no reg cap).
// LDS 38 KB -> still 4 blocks/CU. B-frag reads amortize A 2x better (-8% LDS
// reads), A-stage writes per FLOP halve (-25% writes), xb re-read 13x -> 7x.
// 7 N-tiles, last at bn0=840 (classes 84-99; overlap cols written twice with
// identical values). Grid 128x7 = 896 (896 % 8 == 0, XCD-chunk swizzle).
__global__ __launch_bounds__(256) void k_main(const unsigned short* __restrict__ xb,
                                              const unsigned short* __restrict__ epb,
                                              const float* __restrict__ xsq,
                                              const float* __restrict__ psq,
                                              float* __restrict__ out) {
    __shared__ __align__(16) char smem[38016];
    // A [128][64] @0 (16KB), B [160][64] @16384 (20KB),
    // xsq_s @36864 (512B), psq_s @37376 (640B); epilogue dls[32][161] @0 (20.6KB)
    const int bid = blockIdx.x;                       // 896 blocks
    const int swz = (bid & 7) * 112 + (bid >> 3);     // XCD swizzle (896 % 8 == 0)
    const int bm0 = (swz / 7) * 128;
    const int nt  = swz % 7;
    const int bn0 = (nt < 6) ? nt * 160 : 840;
    const int cls0 = bn0 / 10;
    const int tid = threadIdx.x, lane = tid & 63, wid = tid >> 6;
    const int ls = lane >> 4, lf = lane & 15;
    float* xsq_s = (float*)(smem + 36864);
    float* psq_s = (float*)(smem + 37376);
    if (tid < 128) xsq_s[tid] = xsq[bm0 + tid];
    if (tid < 160) psq_s[tid] = psq[bn0 + tid];

    // staging (rule 21): lane (r=lane>>3, cb=lane&7) loads logical col block
    // (cb ^ r) so the linear LDS write lands at the swizzled slot.
    const int sr = lane >> 3, scb = lane & 7;
    const int scol = ((scb ^ sr) << 3);
    const unsigned short* aptr[4];
    const unsigned short* bptr[5];
#pragma unroll
    for (int i = 0; i < 4; ++i)
        aptr[i] = xb + (size_t)(bm0 + (wid + i * 4) * 8 + sr) * FEAT + scol;
#pragma unroll
    for (int j = 0; j < 5; ++j)
        bptr[j] = epb + (size_t)(bn0 + (wid + j * 4) * 8 + sr) * FEAT + scol;

    // swizzled read offsets: addr = row*128 + ((CB ^ (row&7)) << 4)
    int raA[2], raB[10];
#pragma unroll
    for (int f = 0; f < 2; ++f)  raA[f] = (wid * 32 + f * 16 + lf) * 128;
#pragma unroll
    for (int f = 0; f < 10; ++f) raB[f] = 16384 + (f * 16 + lf) * 128;
    const int sw = lf & 7;

    f32x4 acc[2][10] = {};

    for (int t = 0; t < 16; ++t) {
        __syncthreads();   // previous tile's reads done before overwrite
#pragma unroll
        for (int i = 0; i < 4; ++i)
            gload16(aptr[i], smem + (wid + i * 4) * 1024);
#pragma unroll
        for (int j = 0; j < 5; ++j)
            gload16(bptr[j], smem + 16384 + (wid + j * 4) * 1024);
#pragma unroll
        for (int i = 0; i < 4; ++i) aptr[i] += 64;
#pragma unroll
        for (int j = 0; j < 5; ++j) bptr[j] += 64;
        __syncthreads();   // drains vmcnt -> staged data visible
#pragma unroll
        for (int kk2 = 0; kk2 < 2; ++kk2) {
            const int off = (((kk2 * 4 + ls) ^ sw) << 4);
            short8 a[2], b[10];
#pragma unroll
            for (int f = 0; f < 2; ++f)
                a[f] = *(const short8*)(smem + raA[f] + off);
#pragma unroll
            for (int f = 0; f < 10; ++f)
                b[f] = *(const short8*)(smem + raB[f] + off);
#pragma unroll
            for (int fm = 0; fm < 2; ++fm)
#pragma unroll
                for (int fn = 0; fn < 10; ++fn)
                    acc[fm][fn] = __builtin_amdgcn_mfma_f32_16x16x32_bf16(a[fm], b[fn], acc[fm][fn], 0, 0, 0);
        }
    }

    // epilogue: d = sqrt(max(xsq - 2*dot + psq, 0)); min over groups of 10.
    // 4 passes q = (wave-pair g, fm p): dls[32][161] f32 = 20.6 KB.
    float* dls = (float*)smem;
    const int tr = ls * 4;
#pragma unroll
    for (int q = 0; q < 4; ++q) {
        const int g = q >> 1, p = q & 1;
        __syncthreads();
        if ((wid >> 1) == g) {
#pragma unroll
            for (int fn = 0; fn < 10; ++fn) {
                int col = fn * 16 + lf;
                float pq = psq_s[col];
#pragma unroll
                for (int r = 0; r < 4; ++r) {
                    float d2 = xsq_s[wid * 32 + p * 16 + tr + r] - 2.f * acc[p][fn][r] + pq;
                    dls[((wid & 1) * 16 + tr + r) * 161 + col] = sqrtf(fmaxf(d2, 0.f));
                }
            }
        }
        __syncthreads();
#pragma unroll
        for (int i = 0; i < 2; ++i) {
            int task = tid + i * 256;      // 512 tasks: 32 rows x 16 classes
            int rr = task >> 4, cl = task & 15;
            float m = 1e30f;
#pragma unroll
            for (int j = 0; j < 10; ++j) m = fminf(m, dls[rr * 161 + cl * 10 + j]);
            int grow = bm0 + (g * 2 + (rr >> 4)) * 32 + p * 16 + (rr & 15);
            out[(size_t)grow * NCLS + cls0 + cl] = m;
        }
    }
}

extern "C" void kernel_launch(void* const* d_in, const int* in_sizes, int n_in,
                              void* d_out, int out_size, void* d_ws, size_t ws_size,
                              hipStream_t stream) {
    const float* x      = (const float*)d_in[0];
    const float* protos = (const float*)d_in[1];
    const float* enc_w  = (const float*)d_in[2];
    const float* enc_b  = (const float*)d_in[3];
    float* out = (float*)d_out;
    char* ws = (char*)d_ws;

    unsigned short* xb  = (unsigned short*)ws;                   // 16384*1024*2 = 33554432
    unsigned short* epb = (unsigned short*)(ws + 33554432);      // 1000*1024*2 (2MB slot)
    unsigned short* prb = (unsigned short*)(ws + 35651584);      // 1024*1024*2  = 2097152
    unsigned short* wtb = (unsigned short*)(ws + 37748736);      // 1024*1024*2  = 2097152
    float* xsq = (float*)(ws + 39845888);                        // 16384*4
    float* psq = (float*)(ws + 39911424);                        // 1000*4

    k_prep_all<<<6145, 256, 0, stream>>>(x, xb, xsq, protos, prb, enc_w, wtb, psq);
    k_enc_gemm<<<256, 256, 0, stream>>>(prb, wtb, enc_b, epb, psq);
    k_main<<<896, 256, 0, stream>>>(xb, epb, xsq, psq, out);
}

// Round 21
// 94.469 us; speedup vs baseline: 1.2309x; 1.2309x over previous
//
#include <hip/hip_runtime.h>
#include <hip/hip_bf16.h>
#include <stdint.h>

#define FEAT 1024
#define NALL 1000
#define NCLS 100

typedef __attribute__((ext_vector_type(8))) short short8;
typedef __attribute__((ext_vector_type(4))) float f32x4;
typedef __attribute__((ext_vector_type(4))) unsigned short us4;

__device__ __forceinline__ unsigned short f2bf(float f) {
    union { float f; uint32_t u; } v; v.f = f;
    uint32_t u = v.u;
    return (unsigned short)((u + 0x7FFFu + ((u >> 16) & 1u)) >> 16);
}

__device__ __forceinline__ void gload16(const void* g, void* l) {
    __builtin_amdgcn_global_load_lds((__attribute__((address_space(1))) void*)g,
                                     (__attribute__((address_space(3))) void*)l,
                                     16, 0, 0);
}

// K1 (merged prep): blocks [0,4096): x -> bf16 + row sum-sq
//                   blocks [4096,5120): protos -> bf16 (pad rows 1000.. = 0)
//                   blocks [5120,6144): enc_w transpose -> bf16 wt[n][k]=w[k][n]
//                   block 6144: zero psq
__global__ __launch_bounds__(256) void k_prep_all(const float* __restrict__ x,
                                                  unsigned short* __restrict__ xb,
                                                  float* __restrict__ xsq,
                                                  const float* __restrict__ p,
                                                  unsigned short* __restrict__ pb,
                                                  const float* __restrict__ w,
                                                  unsigned short* __restrict__ wt,
                                                  float* __restrict__ psq) {
    __shared__ float tile[32][33];
    int b = blockIdx.x;
    if (b < 4096) {
        int row = b * 4 + (threadIdx.x >> 6);
        int lane = threadIdx.x & 63;
        const float4* xr = (const float4*)(x + (size_t)row * FEAT);
        float s = 0.f;
#pragma unroll
        for (int i = 0; i < 4; ++i) {
            float4 v = xr[lane + i * 64];
            s += v.x * v.x + v.y * v.y + v.z * v.z + v.w * v.w;
            us4 o;
            o[0] = f2bf(v.x); o[1] = f2bf(v.y); o[2] = f2bf(v.z); o[3] = f2bf(v.w);
            *(us4*)(xb + (size_t)row * FEAT + (size_t)(lane + i * 64) * 4) = o;
        }
#pragma unroll
        for (int off = 32; off; off >>= 1) s += __shfl_xor(s, off);
        if (lane == 0) xsq[row] = s;
    } else if (b < 5120) {
        int row = b - 4096, t = threadIdx.x;
        us4 o;
        if (row < NALL) {
            float4 v = ((const float4*)(p + (size_t)row * FEAT))[t];
            o[0] = f2bf(v.x); o[1] = f2bf(v.y); o[2] = f2bf(v.z); o[3] = f2bf(v.w);
        } else {
            o[0] = 0; o[1] = 0; o[2] = 0; o[3] = 0;
        }
        *(us4*)(pb + (size_t)row * FEAT + (size_t)t * 4) = o;
    } else if (b < 6144) {
        int bb = b - 5120;
        int bx = bb & 31, by = bb >> 5;
        int tx = threadIdx.x & 31, ty = threadIdx.x >> 5;
#pragma unroll
        for (int i = 0; i < 4; ++i) {
            int r = by * 32 + ty + i * 8;
            tile[ty + i * 8][tx] = w[(size_t)r * FEAT + bx * 32 + tx];
        }
        __syncthreads();
#pragma unroll
        for (int i = 0; i < 4; ++i) {
            int r = bx * 32 + ty + i * 8;
            wt[(size_t)r * FEAT + by * 32 + tx] = f2bf(tile[tx][ty + i * 8]);
        }
    } else {
#pragma unroll
        for (int i = 0; i < 4; ++i) {
            int idx = threadIdx.x + i * 256;
            if (idx < NALL) psq[idx] = 0.f;
        }
    }
}

// K2: encoder GEMM ep = protos @ enc_w + b — 64x64 tiles, 256 blocks, with
// FUSED psq (bf16-rounded squares, shfl-reduced, one atomicAdd/row/wave).
// epb rows class-major permuted: n' = (n%100)*10 + n/100.
__global__ __launch_bounds__(256) void k_enc_gemm(const unsigned short* __restrict__ A,
                                                  const unsigned short* __restrict__ B,
                                                  const float* __restrict__ bias,
                                                  unsigned short* __restrict__ epb,
                                                  float* __restrict__ psq) {
    __shared__ __align__(16) char smem[16384];   // A [64][64] @0, B [64][64] @8192
    int bm0 = (blockIdx.x >> 4) * 64;
    int bn0 = (blockIdx.x & 15) * 64;
    int tid = threadIdx.x, lane = tid & 63, wid = tid >> 6;
    int wm = wid >> 1, wn = wid & 1;
    int ls = lane >> 4, lf = lane & 15;
    f32x4 acc[2][2] = {};
    for (int k0 = 0; k0 < FEAT; k0 += 64) {
        __syncthreads();
#pragma unroll
        for (int i = 0; i < 2; ++i) {
            int ci = wid + i * 4;
            int r = ci * 8 + (lane >> 3), c = (lane & 7) * 8;
            gload16(A + (size_t)(bm0 + r) * FEAT + k0 + c, smem + ci * 1024);
            gload16(B + (size_t)(bn0 + r) * FEAT + k0 + c, smem + 8192 + ci * 1024);
        }
        __syncthreads();
#pragma unroll
        for (int kk = 0; kk < 64; kk += 32) {
            short8 a[2], b[2];
#pragma unroll
            for (int f = 0; f < 2; ++f) {
                a[f] = *(const short8*)(smem + (wm * 32 + f * 16 + lf) * 128 + (kk + ls * 8) * 2);
                b[f] = *(const short8*)(smem + 8192 + (wn * 32 + f * 16 + lf) * 128 + (kk + ls * 8) * 2);
            }
#pragma unroll
            for (int fm = 0; fm < 2; ++fm)
#pragma unroll
                for (int fn = 0; fn < 2; ++fn)
                    acc[fm][fn] = __builtin_amdgcn_mfma_f32_16x16x32_bf16(a[fm], b[fn], acc[fm][fn], 0, 0, 0);
        }
    }
    int tr = ls * 4, tc = lf;
    float sq[2][4] = {};
#pragma unroll
    for (int fn = 0; fn < 2; ++fn) {
        int col = bn0 + wn * 32 + fn * 16 + tc;
        float bb = bias[col];
#pragma unroll
        for (int fm = 0; fm < 2; ++fm) {
#pragma unroll
            for (int r = 0; r < 4; ++r) {
                int row = bm0 + wm * 32 + fm * 16 + tr + r;
                if (row < NALL) {
                    unsigned short us = f2bf(acc[fm][fn][r] + bb);
                    union { uint32_t u; float f; } c; c.u = ((uint32_t)us) << 16;
                    sq[fm][r] += c.f * c.f;
                    int pr = (row % 100) * 10 + row / 100;
                    epb[(size_t)pr * FEAT + col] = us;
                }
            }
        }
    }
#pragma unroll
    for (int fm = 0; fm < 2; ++fm)
#pragma unroll
        for (int r = 0; r < 4; ++r) {
            float s = sq[fm][r];
            s += __shfl_xor(s, 1); s += __shfl_xor(s, 2);
            s += __shfl_xor(s, 4); s += __shfl_xor(s, 8);
            int row = bm0 + wm * 32 + fm * 16 + tr + r;
            if (lf == 0 && row < NALL) {
                int pr = (row % 100) * 10 + row / 100;
                atomicAdd(psq + pr, s);
            }
        }
}

// K3: main GEMM + fused sqrt + min-over-10 — frozen best structure (r12/r15/r19).
// BM=128, BN=80, BK=64, 4 waves 4Mx1N, acc[2][5], 27KB LDS, 4 blocks/CU.
// 13 N-tiles, last at bn0=920 (classes 92-99; overlap cols written twice with
// identical values). Grid 128x13 = 1664.
__global__ __launch_bounds__(256, 4) void k_main(const unsigned short* __restrict__ xb,
                                                 const unsigned short* __restrict__ epb,
                                                 const float* __restrict__ xsq,
                                                 const float* __restrict__ psq,
                                                 float* __restrict__ out) {
    __shared__ __align__(16) char smem[27648];
    const int bid = blockIdx.x;                       // 1664 blocks
    const int swz = (bid & 7) * 208 + (bid >> 3);     // XCD swizzle (1664 % 8 == 0)
    const int bm0 = (swz / 13) * 128;
    const int nt  = swz % 13;
    const int bn0 = (nt < 12) ? nt * 80 : 920;
    const int cls0 = (nt < 12) ? nt * 8 : 92;
    const int tid = threadIdx.x, lane = tid & 63, wid = tid >> 6;
    const int ls = lane >> 4, lf = lane & 15;
    float* xsq_s = (float*)(smem + 26624);
    float* psq_s = (float*)(smem + 27136);
    if (tid < 128) xsq_s[tid] = xsq[bm0 + tid];
    if (tid < 80)  psq_s[tid] = psq[bn0 + tid];

    // staging (rule 21): lane (r=lane>>3, cb=lane&7) loads logical col block
    // (cb ^ r) so the linear LDS write lands at the swizzled slot.
    const int sr = lane >> 3, scb = lane & 7;
    const int scol = ((scb ^ sr) << 3);
    const unsigned short* aptr[4];
    const unsigned short* bptr[3];
#pragma unroll
    for (int i = 0; i < 4; ++i)
        aptr[i] = xb + (size_t)(bm0 + (wid + i * 4) * 8 + sr) * FEAT + scol;
#pragma unroll
    for (int j = 0; j < 3; ++j) {
        int cj = wid + j * 4;
        bptr[j] = epb + (size_t)(bn0 + (cj < 10 ? cj : 0) * 8 + sr) * FEAT + scol;
    }

    // swizzled read offsets: addr = row*128 + ((CB ^ (row&7)) << 4)
    int raA[2], raB[5];
#pragma unroll
    for (int f = 0; f < 2; ++f) raA[f] = (wid * 32 + f * 16 + lf) * 128;
#pragma unroll
    for (int f = 0; f < 5; ++f) raB[f] = 16384 + (f * 16 + lf) * 128;
    const int sw = lf & 7;

    f32x4 acc[2][5] = {};

    for (int t = 0; t < 16; ++t) {
        __syncthreads();   // previous tile's reads done before overwrite
#pragma unroll
        for (int i = 0; i < 4; ++i)
            gload16(aptr[i], smem + (wid + i * 4) * 1024);
#pragma unroll
        for (int j = 0; j < 3; ++j) {
            int cj = wid + j * 4;
            if (cj < 10) gload16(bptr[j], smem + 16384 + cj * 1024);
        }
#pragma unroll
        for (int i = 0; i < 4; ++i) aptr[i] += 64;
#pragma unroll
        for (int j = 0; j < 3; ++j) bptr[j] += 64;
        __syncthreads();   // drains vmcnt -> staged data visible
#pragma unroll
        for (int kk2 = 0; kk2 < 2; ++kk2) {
            const int off = (((kk2 * 4 + ls) ^ sw) << 4);
            short8 a[2], b[5];
#pragma unroll
            for (int f = 0; f < 2; ++f)
                a[f] = *(const short8*)(smem + raA[f] + off);
#pragma unroll
            for (int f = 0; f < 5; ++f)
                b[f] = *(const short8*)(smem + raB[f] + off);
#pragma unroll
            for (int fm = 0; fm < 2; ++fm)
#pragma unroll
                for (int fn = 0; fn < 5; ++fn)
                    acc[fm][fn] = __builtin_amdgcn_mfma_f32_16x16x32_bf16(a[fm], b[fn], acc[fm][fn], 0, 0, 0);
        }
    }

    // epilogue: d = sqrt(max(xsq - 2*dot + psq, 0)); min over groups of 10.
    float* dls = (float*)smem;
    const int tr = ls * 4;
#pragma unroll
    for (int p = 0; p < 2; ++p) {
        __syncthreads();
#pragma unroll
        for (int fn = 0; fn < 5; ++fn) {
            int col = fn * 16 + lf;
            float pq = psq_s[col];
#pragma unroll
            for (int r = 0; r < 4; ++r) {
                float d2 = xsq_s[wid * 32 + p * 16 + tr + r] - 2.f * acc[p][fn][r] + pq;
                dls[(wid * 16 + tr + r) * 81 + col] = sqrtf(fmaxf(d2, 0.f));
            }
        }
        __syncthreads();
#pragma unroll
        for (int i = 0; i < 2; ++i) {
            int task = tid + i * 256;      // 512 tasks: 64 rows x 8 classes
            int rr = task >> 3, cl = task & 7;
            float m = 1e30f;
#pragma unroll
            for (int j = 0; j < 10; ++j) m = fminf(m, dls[rr * 81 + cl * 10 + j]);
            int grow = bm0 + (rr >> 4) * 32 + p * 16 + (rr & 15);
            out[(size_t)grow * NCLS + cls0 + cl] = m;
        }
    }
}

extern "C" void kernel_launch(void* const* d_in, const int* in_sizes, int n_in,
                              void* d_out, int out_size, void* d_ws, size_t ws_size,
                              hipStream_t stream) {
    const float* x      = (const float*)d_in[0];
    const float* protos = (const float*)d_in[1];
    const float* enc_w  = (const float*)d_in[2];
    const float* enc_b  = (const float*)d_in[3];
    float* out = (float*)d_out;
    char* ws = (char*)d_ws;

    unsigned short* xb  = (unsigned short*)ws;                   // 16384*1024*2 = 33554432
    unsigned short* epb = (unsigned short*)(ws + 33554432);      // 1000*1024*2 (2MB slot)
    unsigned short* prb = (unsigned short*)(ws + 35651584);      // 1024*1024*2  = 2097152
    unsigned short* wtb = (unsigned short*)(ws + 37748736);      // 1024*1024*2  = 2097152
    float* xsq = (float*)(ws + 39845888);                        // 16384*4
    float* psq = (float*)(ws + 39911424);                        // 1000*4

    k_prep_all<<<6145, 256, 0, stream>>>(x, xb, xsq, protos, prb, enc_w, wtb, psq);
    k_enc_gemm<<<256, 256, 0, stream>>>(prb, wtb, enc_b, epb, psq);
    k_main<<<1664, 256, 0, stream>>>(xb, epb, xsq, psq, out);
}